// Round 18
// baseline (270.554 us; speedup 1.0000x reference)
//
#include <hip/hip_runtime.h>
#include <hip/hip_bf16.h>

typedef __hip_bfloat16 bf16;
typedef __hip_bfloat162 bf16x2;
typedef __attribute__((ext_vector_type(8))) short short8;
typedef __attribute__((ext_vector_type(4))) float f32x4;

__device__ __forceinline__ float bf2f(short v) {
  return __uint_as_float(((unsigned)(unsigned short)v) << 16);
}
__device__ __forceinline__ bf16 rawbf(short v) {
  unsigned short b = (unsigned short)v; return *(bf16*)&b;
}
__device__ __forceinline__ void storeOut(float* p, float v) { *p = v; }
__device__ __forceinline__ void storeOut(bf16* p, float v) { *p = __float2bfloat16(v); }

#define GLOAD_LDS16(g, l)                                              \
  __builtin_amdgcn_global_load_lds(                                    \
      (const __attribute__((address_space(1))) void*)(g),              \
      (__attribute__((address_space(3))) void*)(l), 16, 0, 0)

// ---------------- prep: fp32->bf16 convert of x + both weight transposes ----------------
__global__ __launch_bounds__(256) void prep_kernel(const float* __restrict__ x,
                                                   const float* __restrict__ w_qkv,
                                                   const float* __restrict__ w_proj,
                                                   bf16* __restrict__ xb,
                                                   bf16* __restrict__ wqkvT,
                                                   bf16* __restrict__ wprojT)
{
  int bid = blockIdx.x;
  if (bid < 9408) {                       // cvt: 50176*384 elems, 2048/block
    int i = bid * 256 + threadIdx.x;
    const float4* p = (const float4*)x + (size_t)i * 2;
    float4 a = p[0], b = p[1];
    union { short8 v; bf16 h[8]; } u;
    u.h[0] = __float2bfloat16(a.x); u.h[1] = __float2bfloat16(a.y);
    u.h[2] = __float2bfloat16(a.z); u.h[3] = __float2bfloat16(a.w);
    u.h[4] = __float2bfloat16(b.x); u.h[5] = __float2bfloat16(b.y);
    u.h[6] = __float2bfloat16(b.z); u.h[7] = __float2bfloat16(b.w);
    *((short8*)xb + i) = u.v;
  } else {                                // transposes: 1152*384 + 384*384 elems
    int idx = (bid - 9408) * 256 + threadIdx.x;
    if (idx < 1152 * 384) {
      int n = idx / 384, k = idx - n * 384;
      wqkvT[idx] = __float2bfloat16(w_qkv[(size_t)k * 1152 + n]);
    } else {
      idx -= 1152 * 384;
      int n = idx / 384, k = idx - n * 384;
      wprojT[idx] = __float2bfloat16(w_proj[(size_t)k * 384 + n]);
    }
  }
}

// ---------------- MFMA GEMM: 256x128 tile, 8 waves, BK=64, A-in-LDS, B-from-L2 ------------
// A: verified gload_lds staging + rule-21 swizzle (byte-identical to round-12 path).
// B: panel is L2-resident (<=98 KB/block, 0.9 MB total) -> per-lane direct global
// fragment reads issued BEFORE the barrier (L2 latency hides under the A drain).
// Guide Common-mistake #7: don't LDS-stage what L2-fits. LDS 48->32 KB => 4 blocks/CU.
template<typename TC, bool BIAS>
__global__ __launch_bounds__(512) void gemm_mfma(const bf16* __restrict__ A,
                                                 const bf16* __restrict__ Bt,
                                                 const float* __restrict__ bias,
                                                 TC* __restrict__ C,
                                                 int M, int N, int K, int nbx)
{
  __shared__ __align__(16) bf16 As[256 * 64];   // 32 KB (A only)
  const int tid = threadIdx.x;
  const int wave = tid >> 6, lane = tid & 63;
  const int nwg = gridDim.x;
  const int qc = nwg >> 3, rr = nwg & 7;
  const int xcd = blockIdx.x & 7, jj = blockIdx.x >> 3;
  const int wg = (xcd < rr ? xcd * (qc + 1) : rr * (qc + 1) + (xcd - rr) * qc) + jj;
  const int by = wg / nbx, bx = wg - by * nbx;
  const int bm = by * 256, bn = bx * 128;
  const int wr = wave >> 1, wc = wave & 1;      // 4 x 2 wave grid

  f32x4 acc[4][4] = {};

  const bf16* aP[4];
#pragma unroll
  for (int e = 0; e < 4; ++e) {
    int flat = e * 8192 + tid * 16;
    int r = flat >> 7;
    int q = ((flat >> 4) & 7) ^ (r & 7);
    aP[e] = A + (size_t)(bm + r) * K + q * 8;
  }
  char* AsW = (char*)As + wave * 1024;

  const int lr = lane & 15, lk = lane >> 4;
  const int rbA = (wr * 64 + lr) * 64;
  const int q0 = ((lk    ) ^ (lr & 7)) * 8;
  const int q1 = ((4 + lk) ^ (lr & 7)) * 8;

  // per-lane B fragment base pointers (direct from global/L2)
  const bf16* bRow[4];
#pragma unroll
  for (int j = 0; j < 4; ++j)
    bRow[j] = Bt + (size_t)(bn + wc * 64 + j * 16 + lr) * K + lk * 8;

  for (int k0 = 0; k0 < K; k0 += 64) {
    short8 bf0[4], bf1[4];
#pragma unroll
    for (int j = 0; j < 4; ++j) {               // issue B loads first (no LDS dep)
      bf0[j] = *(const short8*)(bRow[j] + k0);
      bf1[j] = *(const short8*)(bRow[j] + k0 + 32);
    }
#pragma unroll
    for (int e = 0; e < 4; ++e) GLOAD_LDS16(aP[e] + k0, AsW + e * 8192);
    __syncthreads();
    short8 af0[4], af1[4];
#pragma unroll
    for (int i = 0; i < 4; ++i) {
      af0[i] = *(const short8*)(As + rbA + i * 1024 + q0);
      af1[i] = *(const short8*)(As + rbA + i * 1024 + q1);
    }
#pragma unroll
    for (int i = 0; i < 4; ++i)
#pragma unroll
      for (int j = 0; j < 4; ++j) {
        acc[i][j] = __builtin_amdgcn_mfma_f32_16x16x32_bf16(af0[i], bf0[j], acc[i][j], 0, 0, 0);
        acc[i][j] = __builtin_amdgcn_mfma_f32_16x16x32_bf16(af1[i], bf1[j], acc[i][j], 0, 0, 0);
      }
    __syncthreads();
  }

  const int crow = bm + wr * 64 + lk * 4;
  const int ccol = bn + wc * 64 + lr;
#pragma unroll
  for (int j = 0; j < 4; ++j) {
    int col = ccol + j * 16;
    float bv = BIAS ? bias[col] : 0.f;
#pragma unroll
    for (int i = 0; i < 4; ++i)
#pragma unroll
      for (int t = 0; t < 4; ++t) {
        int row = crow + i * 16 + t;
        storeOut(&C[(size_t)row * N + col], acc[i][j][t] + bv);
      }
  }
}

// ---------------- MFMA window attention + fused pooling (template-F body) ----------------
struct AttnP {
  const bf16 *qb, *kb, *vb;
  bf16* out;
  int R, Rw, f, npos, out_cstride, out_coffset, blk0;
};

template<int F>
__device__ __forceinline__ void attn_body(const float* __restrict__ btable,
                                          const AttnP& p, int blk,
                                          bf16* KP, bf16* Vt, float* bias_s)
{
  const int b = blk / p.R, r = blk % p.R;
  const int rh = r / p.Rw, rw = r % p.Rw;
  const int tid = threadIdx.x;
  const int h = tid >> 6, lane = tid & 63;
  const int lr = lane & 15, lk = lane >> 4;
  const int hb = r & 3;
  const float pinv = 1.0f / (float)(F * F);

  if (tid < 169) bias_s[tid] = btable[tid * 4 + hb];

  const size_t gbase = (size_t)b * 3136 * 1152;

#pragma unroll
  for (int c0 = 0; c0 < 4; ++c0) {
    int j = c0 * 256 + tid;
    if (j < 784) {
      int row = j >> 4, r4 = j & 15;
      int hh = r4 >> 2, slot = r4 & 3;
      int r7 = (row * 9363) >> 16, rm = row - r7 * 7;
      const bf16* src = p.kb + gbase +
          ((size_t)((rh * 7 + r7) * F) * 56 + (rw * 7 + rm) * F) * 1152 + hh * 32 + slot * 8;
      short8 ov;
      if (F == 1) {
        ov = *(const short8*)src;
      } else {
        float sum[8] = {}, mx[8];
#pragma unroll
        for (int e = 0; e < 8; ++e) mx[e] = -3.4e38f;
#pragma unroll
        for (int dy = 0; dy < F; ++dy)
#pragma unroll
          for (int dx = 0; dx < F; ++dx) {
            short8 v = *(const short8*)(src + ((size_t)dy * 56 + dx) * 1152);
#pragma unroll
            for (int e = 0; e < 8; ++e) {
              float fv = bf2f(v[e]); sum[e] += fv; mx[e] = fmaxf(mx[e], fv);
            }
          }
        union { short8 v; bf16 hb8[8]; } u;
#pragma unroll
        for (int e = 0; e < 8; ++e) u.hb8[e] = __float2bfloat16(sum[e] * pinv + mx[e]);
        ov = u.v;
      }
      *(short8*)(KP + hh * 4096 + row * 40 + slot * 8) = ov;
    }
  }

#pragma unroll
  for (int c0 = 0; c0 < 4; ++c0) {
    int j = c0 * 256 + tid;
    int pp = j >> 4, r4 = j & 15;
    int hh = r4 >> 2, d8 = r4 & 3;
    bf16 hv[8];
    if (pp < 49) {
      int r7 = (pp * 9363) >> 16, rm = pp - r7 * 7;
      const bf16* src = p.vb + gbase +
          ((size_t)((rh * 7 + r7) * F) * 56 + (rw * 7 + rm) * F) * 1152 + hh * 32 + d8 * 8;
      if (F == 1) {
        short8 v = *(const short8*)src;
#pragma unroll
        for (int e = 0; e < 8; ++e) hv[e] = rawbf(v[e]);
      } else {
        float sum[8] = {}, mx[8];
#pragma unroll
        for (int e = 0; e < 8; ++e) mx[e] = -3.4e38f;
#pragma unroll
        for (int dy = 0; dy < F; ++dy)
#pragma unroll
          for (int dx = 0; dx < F; ++dx) {
            short8 v = *(const short8*)(src + ((size_t)dy * 56 + dx) * 1152);
#pragma unroll
            for (int e = 0; e < 8; ++e) {
              float fv = bf2f(v[e]); sum[e] += fv; mx[e] = fmaxf(mx[e], fv);
            }
          }
#pragma unroll
        for (int e = 0; e < 8; ++e) hv[e] = __float2bfloat16(sum[e] * pinv + mx[e]);
      }
    } else {
#pragma unroll
      for (int e = 0; e < 8; ++e) hv[e] = __float2bfloat16(0.f);
    }
#pragma unroll
    for (int e = 0; e < 8; ++e) {
      int d = d8 * 8 + e;
      Vt[hh * 2048 + d * 64 + ((pp >> 3) ^ (d & 7)) * 8 + (pp & 7)] = hv[e];
    }
  }

  short8 qa[4];
#pragma unroll
  for (int it = 0; it < 4; ++it) {
    int pq = it * 16 + lr; pq = min(pq, 48);
    int r7 = (pq * 9363) >> 16, rm = pq - r7 * 7;
    const bf16* src = p.qb + gbase +
        ((size_t)((rh * 7 + r7) * F) * 56 + (rw * 7 + rm) * F) * 1152 + h * 32 + lk * 8;
    if (F == 1) {
      qa[it] = *(const short8*)src;
    } else {
      float sum[8] = {}, mx[8];
#pragma unroll
      for (int e = 0; e < 8; ++e) mx[e] = -3.4e38f;
#pragma unroll
      for (int dy = 0; dy < F; ++dy)
#pragma unroll
        for (int dx = 0; dx < F; ++dx) {
          short8 v = *(const short8*)(src + ((size_t)dy * 56 + dx) * 1152);
#pragma unroll
          for (int e = 0; e < 8; ++e) {
            float fv = bf2f(v[e]); sum[e] += fv; mx[e] = fmaxf(mx[e], fv);
          }
        }
      union { short8 v; bf16 hb8[8]; } u;
#pragma unroll
      for (int e = 0; e < 8; ++e) u.hb8[e] = __float2bfloat16(sum[e] * pinv + mx[e]);
      qa[it] = u.v;
    }
  }

  __syncthreads();

  f32x4 s[4][4];
  {
    short8 kf[4];
#pragma unroll
    for (int jt = 0; jt < 4; ++jt)
      kf[jt] = *(const short8*)(KP + h * 4096 + (jt * 16 + lr) * 40 + lk * 8);
    const f32x4 z = {0.f, 0.f, 0.f, 0.f};
    __builtin_amdgcn_s_setprio(1);
#pragma unroll
    for (int it = 0; it < 4; ++it)
#pragma unroll
      for (int jt = 0; jt < 4; ++jt)
        s[it][jt] = __builtin_amdgcn_mfma_f32_16x16x32_bf16(qa[it], kf[jt], z, 0, 0, 0);
    __builtin_amdgcn_s_setprio(0);
  }

  const float scale = 0.17677669529663687f;
  const bool colpad = (lr != 0);
  int pp7[4], ppm[4];
#pragma unroll
  for (int jt = 0; jt < 4; ++jt) {
    int pp = min(jt * 16 + lr, 48);
    pp7[jt] = (pp * 9363) >> 16; ppm[jt] = pp - pp7[jt] * 7;
  }
  float sm[4][4];
#pragma unroll
  for (int it = 0; it < 4; ++it)
#pragma unroll
    for (int t = 0; t < 4; ++t) {
      int pq = min(it * 16 + lk * 4 + t, 48);
      int q7 = (pq * 9363) >> 16, qm = pq - q7 * 7;
#pragma unroll
      for (int jt = 0; jt < 4; ++jt) {
        float bv = bias_s[(q7 - pp7[jt] + 6) * 13 + (qm - ppm[jt] + 6)];
        float v = fmaf(s[it][jt][t], scale, bv);
        if (jt == 3 && colpad) v = -1e30f;
        s[it][jt][t] = v;
      }
      float m = fmaxf(fmaxf(s[it][0][t], s[it][1][t]), fmaxf(s[it][2][t], s[it][3][t]));
      m = fmaxf(m, __shfl_xor(m, 1));
      m = fmaxf(m, __shfl_xor(m, 2));
      m = fmaxf(m, __shfl_xor(m, 4));
      m = fmaxf(m, __shfl_xor(m, 8));
      float ssum = 0.f;
#pragma unroll
      for (int jt = 0; jt < 4; ++jt) {
        float e = __expf(s[it][jt][t] - m);
        s[it][jt][t] = e; ssum += e;
      }
      ssum += __shfl_xor(ssum, 1);
      ssum += __shfl_xor(ssum, 2);
      ssum += __shfl_xor(ssum, 4);
      ssum += __shfl_xor(ssum, 8);
      sm[it][t] = 1.0f / ssum;
    }

#pragma unroll
  for (int it = 0; it < 4; ++it)
#pragma unroll
    for (int t = 0; t < 4; ++t) {
      int prow = it * 16 + lk * 4 + t;
#pragma unroll
      for (int jt = 0; jt < 4; ++jt) {
        int slot = (jt * 2 + (lr >> 3)) ^ (prow & 7);
        KP[h * 4096 + prow * 64 + slot * 8 + (lr & 7)] = __float2bfloat16(s[it][jt][t]);
      }
    }
  __syncthreads();

  f32x4 o[4][2] = {};
#pragma unroll
  for (int ks = 0; ks < 2; ++ks) {
    short8 pf[4], vf[2];
#pragma unroll
    for (int it = 0; it < 4; ++it) {
      int prow = it * 16 + lr;
      pf[it] = *(const short8*)(KP + h * 4096 + prow * 64 + ((ks * 4 + lk) ^ (prow & 7)) * 8);
    }
#pragma unroll
    for (int jd = 0; jd < 2; ++jd) {
      int d = jd * 16 + lr;
      vf[jd] = *(const short8*)(Vt + h * 2048 + d * 64 + ((ks * 4 + lk) ^ (d & 7)) * 8);
    }
    __builtin_amdgcn_s_setprio(1);
#pragma unroll
    for (int it = 0; it < 4; ++it)
#pragma unroll
      for (int jd = 0; jd < 2; ++jd)
        o[it][jd] = __builtin_amdgcn_mfma_f32_16x16x32_bf16(pf[it], vf[jd], o[it][jd], 0, 0, 0);
    __builtin_amdgcn_s_setprio(0);
  }

  const int c0 = (r & 3) * 32;
#pragma unroll
  for (int it = 0; it < 4; ++it)
#pragma unroll
    for (int t = 0; t < 4; ++t) {
      int prow = it * 16 + lk * 4 + t;
      if (prow < 49) {
        int m_out = (h * (p.R >> 2) + (r >> 2)) * 49 + prow;
        bf16* op = p.out + ((size_t)b * p.npos + m_out) * p.out_cstride + p.out_coffset + c0;
#pragma unroll
        for (int jd = 0; jd < 2; ++jd)
          op[jd * 16 + lr] = __float2bfloat16(o[it][jd][t] * sm[it][t]);
      }
    }
}

__global__ __launch_bounds__(256) void attn_mfma(const float* __restrict__ btable,
                                                 AttnP P0, AttnP P1, AttnP P2)
{
  __shared__ __align__(16) bf16 KP[4 * 4096];
  __shared__ __align__(16) bf16 Vt[4 * 2048];
  __shared__ float bias_s[169];

  const AttnP p = (blockIdx.x >= (unsigned)P0.blk0) ? P0
                : (blockIdx.x >= (unsigned)P1.blk0) ? P1 : P2;
  const int blk = blockIdx.x - p.blk0;
  if (p.f == 1)      attn_body<1>(btable, p, blk, KP, Vt, bias_s);
  else if (p.f == 2) attn_body<2>(btable, p, blk, KP, Vt, bias_s);
  else               attn_body<4>(btable, p, blk, KP, Vt, bias_s);
}

// ---------------- Fused bilinear upsample for both scales ----------------
__device__ __forceinline__ float2 bilerp2(const bf16* __restrict__ base, int dim, int h, int w, int cp)
{
  float r = (float)dim / 56.f;
  float uy = (h + 0.5f) * r - 0.5f;
  float ux = (w + 0.5f) * r - 0.5f;
  float fy0 = floorf(uy), fx0 = floorf(ux);
  int y0 = (int)fy0, x0 = (int)fx0;
  float fy = uy - fy0, fx = ux - fx0;
  int y0c = max(y0, 0), y1c = min(y0 + 1, dim - 1);
  int x0c = max(x0, 0), x1c = min(x0 + 1, dim - 1);
  bf16x2 v00 = *(const bf16x2*)(base + ((size_t)y0c * dim + x0c) * 128 + cp * 2);
  bf16x2 v01 = *(const bf16x2*)(base + ((size_t)y0c * dim + x1c) * 128 + cp * 2);
  bf16x2 v10 = *(const bf16x2*)(base + ((size_t)y1c * dim + x0c) * 128 + cp * 2);
  bf16x2 v11 = *(const bf16x2*)(base + ((size_t)y1c * dim + x1c) * 128 + cp * 2);
  float w00 = (1.f - fy) * (1.f - fx), w01 = (1.f - fy) * fx;
  float w10 = fy * (1.f - fx),        w11 = fy * fx;
  float2 o;
  o.x = w00 * __bfloat162float(v00.x) + w01 * __bfloat162float(v01.x) +
        w10 * __bfloat162float(v10.x) + w11 * __bfloat162float(v11.x);
  o.y = w00 * __bfloat162float(v00.y) + w01 * __bfloat162float(v01.y) +
        w10 * __bfloat162float(v10.y) + w11 * __bfloat162float(v11.y);
  return o;
}

__global__ __launch_bounds__(256) void upsample_both_kernel(const bf16* __restrict__ yb1,
                                                            const bf16* __restrict__ yb2,
                                                            bf16* __restrict__ fused)
{
  int t = blockIdx.x * 256 + threadIdx.x;
  int cp = t & 63;
  int pos = t >> 6;
  int n = pos % 3136, b = pos / 3136;
  int h = n / 56, w = n % 56;
  float2 s1 = bilerp2(yb1 + (size_t)b * 784 * 128, 28, h, w, cp);
  float2 s2 = bilerp2(yb2 + (size_t)b * 196 * 128, 14, h, w, cp);
  bf16* op = fused + (size_t)pos * 384;
  bf16x2 o1; o1.x = __float2bfloat16(s1.x); o1.y = __float2bfloat16(s1.y);
  bf16x2 o2; o2.x = __float2bfloat16(s2.x); o2.y = __float2bfloat16(s2.y);
  *(bf16x2*)(op + 128 + cp * 2) = o1;
  *(bf16x2*)(op + 256 + cp * 2) = o2;
}

extern "C" void kernel_launch(void* const* d_in, const int* in_sizes, int n_in,
                              void* d_out, int out_size, void* d_ws, size_t ws_size,
                              hipStream_t stream)
{
  const float* x      = (const float*)d_in[0];
  const float* w_qkv  = (const float*)d_in[1];
  const float* w_proj = (const float*)d_in[2];
  const float* b_proj = (const float*)d_in[3];
  const float* btable = (const float*)d_in[4];

  bf16* temp  = (bf16*)d_ws;                          // 50176 x 1152
  bf16* fused = temp  + (size_t)50176 * 1152 + (size_t)3 * 16 * 980 * 128;
  bf16* ybuf1 = fused + (size_t)50176 * 384;          // 16 x 784 x 128
  bf16* ybuf2 = ybuf1 + (size_t)16 * 784 * 128;       // 16 x 196 x 128
  bf16* wqkvT = ybuf2 + (size_t)16 * 196 * 128;       // 1152 x 384
  bf16* wprojT= wqkvT + (size_t)1152 * 384;           // 384 x 384
  bf16* xb    = fused;   // x in bf16, dead before attention writes fused

  // 0) prep: cvt + transposes in one launch
  prep_kernel<<<9408 + 2304, 256, 0, stream>>>(x, w_qkv, w_proj, xb, wqkvT, wprojT);

  // 1) QKV projection: temp = xb @ wqkvT^T  (196 x 9 = 1764 blocks, 512 thr)
  gemm_mfma<bf16, false><<<1764, 512, 0, stream>>>(
      xb, wqkvT, nullptr, temp, 50176, 1152, 384, 9);

  // 2) MFMA window attention with fused pooling; heavy f=4 blocks first
  AttnP P2{temp + 256, temp + 640, temp + 1024, ybuf2,
           4, 2, 4, 196, 128, 0, 0};
  AttnP P1{temp + 128, temp + 512, temp + 896, ybuf1,
           16, 4, 2, 784, 128, 0, 64};
  AttnP P0{temp, temp + 384, temp + 768, fused,
           64, 8, 1, 3136, 384, 0, 320};
  attn_mfma<<<1344, 256, 0, stream>>>(btable, P0, P1, P2);

  // 3) fused bilinear upsample into fused channels [128,256) and [256,384)
  upsample_both_kernel<<<16 * 3136 * 64 / 256, 256, 0, stream>>>(ybuf1, ybuf2, fused);

  // 4) output projection: out = fused @ wprojT^T + b_proj (196 x 3 = 588 blocks)
  gemm_mfma<float, true><<<588, 512, 0, stream>>>(
      fused, wprojT, b_proj, (float*)d_out, 50176, 384, 384, 3);
}

// Round 19
// 171.364 us; speedup vs baseline: 1.5788x; 1.5788x over previous
//
#include <hip/hip_runtime.h>
#include <hip/hip_bf16.h>

typedef __hip_bfloat16 bf16;
typedef __hip_bfloat162 bf16x2;
typedef __attribute__((ext_vector_type(8))) short short8;
typedef __attribute__((ext_vector_type(4))) float f32x4;

__device__ __forceinline__ float bf2f(short v) {
  return __uint_as_float(((unsigned)(unsigned short)v) << 16);
}
__device__ __forceinline__ bf16 rawbf(short v) {
  unsigned short b = (unsigned short)v; return *(bf16*)&b;
}
__device__ __forceinline__ void storeOut(float* p, float v) { *p = v; }
__device__ __forceinline__ void storeOut(bf16* p, float v) { *p = __float2bfloat16(v); }

#define GLOAD_LDS16(g, l)                                              \
  __builtin_amdgcn_global_load_lds(                                    \
      (const __attribute__((address_space(1))) void*)(g),              \
      (__attribute__((address_space(3))) void*)(l), 16, 0, 0)

// ---------------- prep: fp32->bf16 convert of x + both weight transposes ----------------
__global__ __launch_bounds__(256) void prep_kernel(const float* __restrict__ x,
                                                   const float* __restrict__ w_qkv,
                                                   const float* __restrict__ w_proj,
                                                   bf16* __restrict__ xb,
                                                   bf16* __restrict__ wqkvT,
                                                   bf16* __restrict__ wprojT)
{
  int bid = blockIdx.x;
  if (bid < 9408) {                       // cvt: 50176*384 elems, 2048/block
    int i = bid * 256 + threadIdx.x;
    const float4* p = (const float4*)x + (size_t)i * 2;
    float4 a = p[0], b = p[1];
    union { short8 v; bf16 h[8]; } u;
    u.h[0] = __float2bfloat16(a.x); u.h[1] = __float2bfloat16(a.y);
    u.h[2] = __float2bfloat16(a.z); u.h[3] = __float2bfloat16(a.w);
    u.h[4] = __float2bfloat16(b.x); u.h[5] = __float2bfloat16(b.y);
    u.h[6] = __float2bfloat16(b.z); u.h[7] = __float2bfloat16(b.w);
    *((short8*)xb + i) = u.v;
  } else {                                // transposes: 1152*384 + 384*384 elems
    int idx = (bid - 9408) * 256 + threadIdx.x;
    if (idx < 1152 * 384) {
      int n = idx / 384, k = idx - n * 384;
      wqkvT[idx] = __float2bfloat16(w_qkv[(size_t)k * 1152 + n]);
    } else {
      idx -= 1152 * 384;
      int n = idx / 384, k = idx - n * 384;
      wprojT[idx] = __float2bfloat16(w_proj[(size_t)k * 384 + n]);
    }
  }
}

// ---------------- MFMA GEMM: 256x128 tile, 8 waves, BK=64, single-buffer ----------------
// Verified best (r12/r17: 64 us GEMM1). 2-phase structural ceiling: pipelining
// (r10/r13/r14), tile variants (r9/r15), tail rewrite (r16), B-unstaged (r18)
// all regressed vs this exact configuration.
template<typename TC, bool BIAS>
__global__ __launch_bounds__(512) void gemm_mfma(const bf16* __restrict__ A,
                                                 const bf16* __restrict__ Bt,
                                                 const float* __restrict__ bias,
                                                 TC* __restrict__ C,
                                                 int M, int N, int K, int nbx)
{
  __shared__ __align__(16) bf16 As[256 * 64];   // 32 KB
  __shared__ __align__(16) bf16 Bs[128 * 64];   // 16 KB
  const int tid = threadIdx.x;
  const int wave = tid >> 6, lane = tid & 63;
  const int nwg = gridDim.x;
  const int qc = nwg >> 3, rr = nwg & 7;
  const int xcd = blockIdx.x & 7, jj = blockIdx.x >> 3;
  const int wg = (xcd < rr ? xcd * (qc + 1) : rr * (qc + 1) + (xcd - rr) * qc) + jj;
  const int by = wg / nbx, bx = wg - by * nbx;
  const int bm = by * 256, bn = bx * 128;
  const int wr = wave >> 1, wc = wave & 1;      // 4 x 2 wave grid

  f32x4 acc[4][4] = {};

  const bf16* aP[4];
  const bf16* bP[2];
#pragma unroll
  for (int e = 0; e < 4; ++e) {
    int flat = e * 8192 + tid * 16;
    int r = flat >> 7;
    int q = ((flat >> 4) & 7) ^ (r & 7);
    aP[e] = A + (size_t)(bm + r) * K + q * 8;
  }
#pragma unroll
  for (int e = 0; e < 2; ++e) {
    int flat = e * 8192 + tid * 16;
    int r = flat >> 7;
    int q = ((flat >> 4) & 7) ^ (r & 7);
    bP[e] = Bt + (size_t)(bn + r) * K + q * 8;
  }
  char* AsW = (char*)As + wave * 1024;
  char* BsW = (char*)Bs + wave * 1024;

  const int lr = lane & 15, lk = lane >> 4;
  const int rbA = (wr * 64 + lr) * 64;
  const int rbB = (wc * 64 + lr) * 64;
  const int q0 = ((lk    ) ^ (lr & 7)) * 8;
  const int q1 = ((4 + lk) ^ (lr & 7)) * 8;

  for (int k0 = 0; k0 < K; k0 += 64) {
#pragma unroll
    for (int e = 0; e < 4; ++e) GLOAD_LDS16(aP[e] + k0, AsW + e * 8192);
#pragma unroll
    for (int e = 0; e < 2; ++e) GLOAD_LDS16(bP[e] + k0, BsW + e * 8192);
    __syncthreads();
    short8 af0[4], af1[4], bf0[4], bf1[4];
#pragma unroll
    for (int i = 0; i < 4; ++i) {
      af0[i] = *(const short8*)(As + rbA + i * 1024 + q0);
      af1[i] = *(const short8*)(As + rbA + i * 1024 + q1);
    }
#pragma unroll
    for (int j = 0; j < 4; ++j) {
      bf0[j] = *(const short8*)(Bs + rbB + j * 1024 + q0);
      bf1[j] = *(const short8*)(Bs + rbB + j * 1024 + q1);
    }
#pragma unroll
    for (int i = 0; i < 4; ++i)
#pragma unroll
      for (int j = 0; j < 4; ++j) {
        acc[i][j] = __builtin_amdgcn_mfma_f32_16x16x32_bf16(af0[i], bf0[j], acc[i][j], 0, 0, 0);
        acc[i][j] = __builtin_amdgcn_mfma_f32_16x16x32_bf16(af1[i], bf1[j], acc[i][j], 0, 0, 0);
      }
    __syncthreads();
  }

  const int crow = bm + wr * 64 + lk * 4;
  const int ccol = bn + wc * 64 + lr;
#pragma unroll
  for (int j = 0; j < 4; ++j) {
    int col = ccol + j * 16;
    float bv = BIAS ? bias[col] : 0.f;
#pragma unroll
    for (int i = 0; i < 4; ++i)
#pragma unroll
      for (int t = 0; t < 4; ++t) {
        int row = crow + i * 16 + t;
        storeOut(&C[(size_t)row * N + col], acc[i][j][t] + bv);
      }
  }
}

// ---------------- MFMA window attention + fused pooling (template-F body) ----------------
struct AttnP {
  const bf16 *qb, *kb, *vb;
  bf16* out;
  int R, Rw, f, npos, out_cstride, out_coffset, blk0;
};

template<int F>
__device__ __forceinline__ void attn_body(const float* __restrict__ btable,
                                          const AttnP& p, int blk,
                                          bf16* KP, bf16* Vt, float* bias_s)
{
  const int b = blk / p.R, r = blk % p.R;
  const int rh = r / p.Rw, rw = r % p.Rw;
  const int tid = threadIdx.x;
  const int h = tid >> 6, lane = tid & 63;
  const int lr = lane & 15, lk = lane >> 4;
  const int hb = r & 3;
  const float pinv = 1.0f / (float)(F * F);

  if (tid < 169) bias_s[tid] = btable[tid * 4 + hb];

  const size_t gbase = (size_t)b * 3136 * 1152;

#pragma unroll
  for (int c0 = 0; c0 < 4; ++c0) {
    int j = c0 * 256 + tid;
    if (j < 784) {
      int row = j >> 4, r4 = j & 15;
      int hh = r4 >> 2, slot = r4 & 3;
      int r7 = (row * 9363) >> 16, rm = row - r7 * 7;
      const bf16* src = p.kb + gbase +
          ((size_t)((rh * 7 + r7) * F) * 56 + (rw * 7 + rm) * F) * 1152 + hh * 32 + slot * 8;
      short8 ov;
      if (F == 1) {
        ov = *(const short8*)src;
      } else {
        float sum[8] = {}, mx[8];
#pragma unroll
        for (int e = 0; e < 8; ++e) mx[e] = -3.4e38f;
#pragma unroll
        for (int dy = 0; dy < F; ++dy)
#pragma unroll
          for (int dx = 0; dx < F; ++dx) {
            short8 v = *(const short8*)(src + ((size_t)dy * 56 + dx) * 1152);
#pragma unroll
            for (int e = 0; e < 8; ++e) {
              float fv = bf2f(v[e]); sum[e] += fv; mx[e] = fmaxf(mx[e], fv);
            }
          }
        union { short8 v; bf16 hb8[8]; } u;
#pragma unroll
        for (int e = 0; e < 8; ++e) u.hb8[e] = __float2bfloat16(sum[e] * pinv + mx[e]);
        ov = u.v;
      }
      *(short8*)(KP + hh * 4096 + row * 40 + slot * 8) = ov;
    }
  }

#pragma unroll
  for (int c0 = 0; c0 < 4; ++c0) {
    int j = c0 * 256 + tid;
    int pp = j >> 4, r4 = j & 15;
    int hh = r4 >> 2, d8 = r4 & 3;
    bf16 hv[8];
    if (pp < 49) {
      int r7 = (pp * 9363) >> 16, rm = pp - r7 * 7;
      const bf16* src = p.vb + gbase +
          ((size_t)((rh * 7 + r7) * F) * 56 + (rw * 7 + rm) * F) * 1152 + hh * 32 + d8 * 8;
      if (F == 1) {
        short8 v = *(const short8*)src;
#pragma unroll
        for (int e = 0; e < 8; ++e) hv[e] = rawbf(v[e]);
      } else {
        float sum[8] = {}, mx[8];
#pragma unroll
        for (int e = 0; e < 8; ++e) mx[e] = -3.4e38f;
#pragma unroll
        for (int dy = 0; dy < F; ++dy)
#pragma unroll
          for (int dx = 0; dx < F; ++dx) {
            short8 v = *(const short8*)(src + ((size_t)dy * 56 + dx) * 1152);
#pragma unroll
            for (int e = 0; e < 8; ++e) {
              float fv = bf2f(v[e]); sum[e] += fv; mx[e] = fmaxf(mx[e], fv);
            }
          }
#pragma unroll
        for (int e = 0; e < 8; ++e) hv[e] = __float2bfloat16(sum[e] * pinv + mx[e]);
      }
    } else {
#pragma unroll
      for (int e = 0; e < 8; ++e) hv[e] = __float2bfloat16(0.f);
    }
#pragma unroll
    for (int e = 0; e < 8; ++e) {
      int d = d8 * 8 + e;
      Vt[hh * 2048 + d * 64 + ((pp >> 3) ^ (d & 7)) * 8 + (pp & 7)] = hv[e];
    }
  }

  short8 qa[4];
#pragma unroll
  for (int it = 0; it < 4; ++it) {
    int pq = it * 16 + lr; pq = min(pq, 48);
    int r7 = (pq * 9363) >> 16, rm = pq - r7 * 7;
    const bf16* src = p.qb + gbase +
        ((size_t)((rh * 7 + r7) * F) * 56 + (rw * 7 + rm) * F) * 1152 + h * 32 + lk * 8;
    if (F == 1) {
      qa[it] = *(const short8*)src;
    } else {
      float sum[8] = {}, mx[8];
#pragma unroll
      for (int e = 0; e < 8; ++e) mx[e] = -3.4e38f;
#pragma unroll
      for (int dy = 0; dy < F; ++dy)
#pragma unroll
        for (int dx = 0; dx < F; ++dx) {
          short8 v = *(const short8*)(src + ((size_t)dy * 56 + dx) * 1152);
#pragma unroll
          for (int e = 0; e < 8; ++e) {
            float fv = bf2f(v[e]); sum[e] += fv; mx[e] = fmaxf(mx[e], fv);
          }
        }
      union { short8 v; bf16 hb8[8]; } u;
#pragma unroll
      for (int e = 0; e < 8; ++e) u.hb8[e] = __float2bfloat16(sum[e] * pinv + mx[e]);
      qa[it] = u.v;
    }
  }

  __syncthreads();

  f32x4 s[4][4];
  {
    short8 kf[4];
#pragma unroll
    for (int jt = 0; jt < 4; ++jt)
      kf[jt] = *(const short8*)(KP + h * 4096 + (jt * 16 + lr) * 40 + lk * 8);
    const f32x4 z = {0.f, 0.f, 0.f, 0.f};
    __builtin_amdgcn_s_setprio(1);
#pragma unroll
    for (int it = 0; it < 4; ++it)
#pragma unroll
      for (int jt = 0; jt < 4; ++jt)
        s[it][jt] = __builtin_amdgcn_mfma_f32_16x16x32_bf16(qa[it], kf[jt], z, 0, 0, 0);
    __builtin_amdgcn_s_setprio(0);
  }

  const float scale = 0.17677669529663687f;
  const bool colpad = (lr != 0);
  int pp7[4], ppm[4];
#pragma unroll
  for (int jt = 0; jt < 4; ++jt) {
    int pp = min(jt * 16 + lr, 48);
    pp7[jt] = (pp * 9363) >> 16; ppm[jt] = pp - pp7[jt] * 7;
  }
  float sm[4][4];
#pragma unroll
  for (int it = 0; it < 4; ++it)
#pragma unroll
    for (int t = 0; t < 4; ++t) {
      int pq = min(it * 16 + lk * 4 + t, 48);
      int q7 = (pq * 9363) >> 16, qm = pq - q7 * 7;
#pragma unroll
      for (int jt = 0; jt < 4; ++jt) {
        float bv = bias_s[(q7 - pp7[jt] + 6) * 13 + (qm - ppm[jt] + 6)];
        float v = fmaf(s[it][jt][t], scale, bv);
        if (jt == 3 && colpad) v = -1e30f;
        s[it][jt][t] = v;
      }
      float m = fmaxf(fmaxf(s[it][0][t], s[it][1][t]), fmaxf(s[it][2][t], s[it][3][t]));
      m = fmaxf(m, __shfl_xor(m, 1));
      m = fmaxf(m, __shfl_xor(m, 2));
      m = fmaxf(m, __shfl_xor(m, 4));
      m = fmaxf(m, __shfl_xor(m, 8));
      float ssum = 0.f;
#pragma unroll
      for (int jt = 0; jt < 4; ++jt) {
        float e = __expf(s[it][jt][t] - m);
        s[it][jt][t] = e; ssum += e;
      }
      ssum += __shfl_xor(ssum, 1);
      ssum += __shfl_xor(ssum, 2);
      ssum += __shfl_xor(ssum, 4);
      ssum += __shfl_xor(ssum, 8);
      sm[it][t] = 1.0f / ssum;
    }

#pragma unroll
  for (int it = 0; it < 4; ++it)
#pragma unroll
    for (int t = 0; t < 4; ++t) {
      int prow = it * 16 + lk * 4 + t;
#pragma unroll
      for (int jt = 0; jt < 4; ++jt) {
        int slot = (jt * 2 + (lr >> 3)) ^ (prow & 7);
        KP[h * 4096 + prow * 64 + slot * 8 + (lr & 7)] = __float2bfloat16(s[it][jt][t]);
      }
    }
  __syncthreads();

  f32x4 o[4][2] = {};
#pragma unroll
  for (int ks = 0; ks < 2; ++ks) {
    short8 pf[4], vf[2];
#pragma unroll
    for (int it = 0; it < 4; ++it) {
      int prow = it * 16 + lr;
      pf[it] = *(const short8*)(KP + h * 4096 + prow * 64 + ((ks * 4 + lk) ^ (prow & 7)) * 8);
    }
#pragma unroll
    for (int jd = 0; jd < 2; ++jd) {
      int d = jd * 16 + lr;
      vf[jd] = *(const short8*)(Vt + h * 2048 + d * 64 + ((ks * 4 + lk) ^ (d & 7)) * 8);
    }
    __builtin_amdgcn_s_setprio(1);
#pragma unroll
    for (int it = 0; it < 4; ++it)
#pragma unroll
      for (int jd = 0; jd < 2; ++jd)
        o[it][jd] = __builtin_amdgcn_mfma_f32_16x16x32_bf16(pf[it], vf[jd], o[it][jd], 0, 0, 0);
    __builtin_amdgcn_s_setprio(0);
  }

  const int c0 = (r & 3) * 32;
#pragma unroll
  for (int it = 0; it < 4; ++it)
#pragma unroll
    for (int t = 0; t < 4; ++t) {
      int prow = it * 16 + lk * 4 + t;
      if (prow < 49) {
        int m_out = (h * (p.R >> 2) + (r >> 2)) * 49 + prow;
        bf16* op = p.out + ((size_t)b * p.npos + m_out) * p.out_cstride + p.out_coffset + c0;
#pragma unroll
        for (int jd = 0; jd < 2; ++jd)
          op[jd * 16 + lr] = __float2bfloat16(o[it][jd][t] * sm[it][t]);
      }
    }
}

__global__ __launch_bounds__(256) void attn_mfma(const float* __restrict__ btable,
                                                 AttnP P0, AttnP P1, AttnP P2)
{
  __shared__ __align__(16) bf16 KP[4 * 4096];
  __shared__ __align__(16) bf16 Vt[4 * 2048];
  __shared__ float bias_s[169];

  const AttnP p = (blockIdx.x >= (unsigned)P0.blk0) ? P0
                : (blockIdx.x >= (unsigned)P1.blk0) ? P1 : P2;
  const int blk = blockIdx.x - p.blk0;
  if (p.f == 1)      attn_body<1>(btable, p, blk, KP, Vt, bias_s);
  else if (p.f == 2) attn_body<2>(btable, p, blk, KP, Vt, bias_s);
  else               attn_body<4>(btable, p, blk, KP, Vt, bias_s);
}

// ---------------- Fused bilinear upsample for both scales ----------------
__device__ __forceinline__ float2 bilerp2(const bf16* __restrict__ base, int dim, int h, int w, int cp)
{
  float r = (float)dim / 56.f;
  float uy = (h + 0.5f) * r - 0.5f;
  float ux = (w + 0.5f) * r - 0.5f;
  float fy0 = floorf(uy), fx0 = floorf(ux);
  int y0 = (int)fy0, x0 = (int)fx0;
  float fy = uy - fy0, fx = ux - fx0;
  int y0c = max(y0, 0), y1c = min(y0 + 1, dim - 1);
  int x0c = max(x0, 0), x1c = min(x0 + 1, dim - 1);
  bf16x2 v00 = *(const bf16x2*)(base + ((size_t)y0c * dim + x0c) * 128 + cp * 2);
  bf16x2 v01 = *(const bf16x2*)(base + ((size_t)y0c * dim + x1c) * 128 + cp * 2);
  bf16x2 v10 = *(const bf16x2*)(base + ((size_t)y1c * dim + x0c) * 128 + cp * 2);
  bf16x2 v11 = *(const bf16x2*)(base + ((size_t)y1c * dim + x1c) * 128 + cp * 2);
  float w00 = (1.f - fy) * (1.f - fx), w01 = (1.f - fy) * fx;
  float w10 = fy * (1.f - fx),        w11 = fy * fx;
  float2 o;
  o.x = w00 * __bfloat162float(v00.x) + w01 * __bfloat162float(v01.x) +
        w10 * __bfloat162float(v10.x) + w11 * __bfloat162float(v11.x);
  o.y = w00 * __bfloat162float(v00.y) + w01 * __bfloat162float(v01.y) +
        w10 * __bfloat162float(v10.y) + w11 * __bfloat162float(v11.y);
  return o;
}

__global__ __launch_bounds__(256) void upsample_both_kernel(const bf16* __restrict__ yb1,
                                                            const bf16* __restrict__ yb2,
                                                            bf16* __restrict__ fused)
{
  int t = blockIdx.x * 256 + threadIdx.x;
  int cp = t & 63;
  int pos = t >> 6;
  int n = pos % 3136, b = pos / 3136;
  int h = n / 56, w = n % 56;
  float2 s1 = bilerp2(yb1 + (size_t)b * 784 * 128, 28, h, w, cp);
  float2 s2 = bilerp2(yb2 + (size_t)b * 196 * 128, 14, h, w, cp);
  bf16* op = fused + (size_t)pos * 384;
  bf16x2 o1; o1.x = __float2bfloat16(s1.x); o1.y = __float2bfloat16(s1.y);
  bf16x2 o2; o2.x = __float2bfloat16(s2.x); o2.y = __float2bfloat16(s2.y);
  *(bf16x2*)(op + 128 + cp * 2) = o1;
  *(bf16x2*)(op + 256 + cp * 2) = o2;
}

extern "C" void kernel_launch(void* const* d_in, const int* in_sizes, int n_in,
                              void* d_out, int out_size, void* d_ws, size_t ws_size,
                              hipStream_t stream)
{
  const float* x      = (const float*)d_in[0];
  const float* w_qkv  = (const float*)d_in[1];
  const float* w_proj = (const float*)d_in[2];
  const float* b_proj = (const float*)d_in[3];
  const float* btable = (const float*)d_in[4];

  bf16* temp  = (bf16*)d_ws;                          // 50176 x 1152
  bf16* fused = temp  + (size_t)50176 * 1152 + (size_t)3 * 16 * 980 * 128;
  bf16* ybuf1 = fused + (size_t)50176 * 384;          // 16 x 784 x 128
  bf16* ybuf2 = ybuf1 + (size_t)16 * 784 * 128;       // 16 x 196 x 128
  bf16* wqkvT = ybuf2 + (size_t)16 * 196 * 128;       // 1152 x 384
  bf16* wprojT= wqkvT + (size_t)1152 * 384;           // 384 x 384
  bf16* xb    = fused;   // x in bf16, dead before attention writes fused

  // 0) prep: cvt + transposes in one launch
  prep_kernel<<<9408 + 2304, 256, 0, stream>>>(x, w_qkv, w_proj, xb, wqkvT, wprojT);

  // 1) QKV projection: temp = xb @ wqkvT^T  (196 x 9 = 1764 blocks, 512 thr)
  gemm_mfma<bf16, false><<<1764, 512, 0, stream>>>(
      xb, wqkvT, nullptr, temp, 50176, 1152, 384, 9);

  // 2) MFMA window attention with fused pooling; heavy f=4 blocks first
  AttnP P2{temp + 256, temp + 640, temp + 1024, ybuf2,
           4, 2, 4, 196, 128, 0, 0};
  AttnP P1{temp + 128, temp + 512, temp + 896, ybuf1,
           16, 4, 2, 784, 128, 0, 64};
  AttnP P0{temp, temp + 384, temp + 768, fused,
           64, 8, 1, 3136, 384, 0, 320};
  attn_mfma<<<1344, 256, 0, stream>>>(btable, P0, P1, P2);

  // 3) fused bilinear upsample into fused channels [128,256) and [256,384)
  upsample_both_kernel<<<16 * 3136 * 64 / 256, 256, 0, stream>>>(ybuf1, ybuf2, fused);

  // 4) output projection: out = fused @ wprojT^T + b_proj (196 x 3 = 588 blocks)
  gemm_mfma<float, true><<<588, 512, 0, stream>>>(
      fused, wprojT, b_proj, (float*)d_out, 50176, 384, 384, 3);
}